// Round 11
// baseline (275.524 us; speedup 1.0000x reference)
//
#include <hip/hip_runtime.h>

// Problem constants
#define B_  4
#define S_  2048
#define D_  1024
#define H_  16
#define DH_ 64
#define M_  (B_*S_)   // 8192

typedef __bf16 bf8_t __attribute__((ext_vector_type(8)));
typedef float f4_t __attribute__((ext_vector_type(4)));
typedef unsigned short u16x8_t __attribute__((ext_vector_type(8)));
typedef unsigned int u32x4_t __attribute__((ext_vector_type(4)));

static __device__ __forceinline__ unsigned short f2bf(float f) {
  return __builtin_bit_cast(unsigned short, (__bf16)f);
}
static __device__ __forceinline__ bf8_t ldbf8(const unsigned short* p) {
  return __builtin_bit_cast(bf8_t, *(const u16x8_t*)p);
}
// pack two f32 -> (bf16(b)<<16)|bf16(a): single VOP3 cvt_pk (RNE)
static __device__ __forceinline__ unsigned int pkbf(float a, float b) {
  unsigned int r;
  asm("v_cvt_pk_bf16_f32 %0, %1, %2" : "=v"(r) : "v"(a), "v"(b));
  return r;
}
#define MFMA16(a,b,c) __builtin_amdgcn_mfma_f32_16x16x32_bf16((a),(b),(c),0,0,0)
#define GLDS16(gp, lp) __builtin_amdgcn_global_load_lds( \
    (const __attribute__((address_space(1))) void*)(gp), \
    (__attribute__((address_space(3))) void*)(lp), 16, 0, 0)
#define SBAR() asm volatile("s_barrier" ::: "memory")
#define LGKM0() asm volatile("s_waitcnt lgkmcnt(0)" ::: "memory")

// 0.125 (1/sqrt(dh)) * log2(e): folded into Q so softmax uses bare exp2.
#define QSCALE 0.18033688011112042f

// ---------------- fused convert kernel ----------------
// blocks [0,8192): x->bf16 (coalesced both sides)
// blocks [8192,8576): Wq/Wk/Wv -> Wcat^T via LDS tile (64dh x 128k per block)
// blocks [8576,8640): Wo -> Wot^T via LDS tile (128x128)

__global__ void cvt_all(const float* __restrict__ x,
                        const float* __restrict__ Wq, const float* __restrict__ Wk,
                        const float* __restrict__ Wv, const float* __restrict__ Wo,
                        unsigned short* __restrict__ xb, unsigned short* __restrict__ Wcat,
                        unsigned short* __restrict__ Wot) {
  __shared__ unsigned short T[128 * 130];             // 33.3 KB, used by transpose parts
  const int blk = blockIdx.x, tid = threadIdx.x;
  if (blk < 8192) {
    int i = blk * 256 + tid;                          // over M_*D_/4
    float4 v = ((const float4*)x)[i];
    unsigned int lo = f2bf(v.x) | ((unsigned int)f2bf(v.y) << 16);
    unsigned int hi = f2bf(v.z) | ((unsigned int)f2bf(v.w) << 16);
    ((uint2*)xb)[i] = make_uint2(lo, hi);
  } else if (blk < 8576) {
    // W (H,D,DH) slab: qkv/h from bid>>3, k-chunk 128 from bid&7.
    int bid = blk - 8192;
    int qh = bid >> 3, kc = bid & 7;
    int qkv = qh >> 4, h = qh & 15;
    const float* W = (qkv == 0) ? Wq : (qkv == 1 ? Wk : Wv);
    const float* src = W + (size_t)h * 65536 + (size_t)kc * 128 * 64;
    // load 128k x 64dh coalesced -> T[k][dh] (pad 66)
#pragma unroll
    for (int jj = 0; jj < 32; jj++) {
      int idx = jj * 256 + tid;                       // kl = idx>>6, dh = idx&63
      T[(idx >> 6) * 66 + (idx & 63)] = f2bf(src[idx]);
    }
    __syncthreads();
    // gather columns -> coalesced 16B writes: Wcat[n0+dh][kc*128 + k]
    int n0 = qkv * 1024 + h * 64;
#pragma unroll
    for (int it = 0; it < 4; it++) {
      int u = it * 256 + tid;                         // 0..1023
      int dh = u >> 4, k8 = (u & 15) * 8;
      unsigned short v[8];
#pragma unroll
      for (int ii = 0; ii < 8; ii++) v[ii] = T[(k8 + ii) * 66 + dh];
      *(u16x8_t*)&Wcat[(size_t)(n0 + dh) * 1024 + kc * 128 + k8] =
          *(const u16x8_t*)v;
    }
  } else {
    // Wo (D,D) row-major -> Wot[n][k]; 128x128 tile
    int bid = blk - 8576;
    int r0 = (bid >> 3) * 128, c0 = (bid & 7) * 128;  // r0: k-dim, c0: n-dim
#pragma unroll
    for (int jj = 0; jj < 64; jj++) {
      int idx = jj * 256 + tid;                       // i = idx>>7, j = idx&127
      int i = idx >> 7, j = idx & 127;
      T[i * 130 + j] = f2bf(Wo[(size_t)(r0 + i) * 1024 + c0 + j]);
    }
    __syncthreads();
#pragma unroll
    for (int it = 0; it < 8; it++) {
      int u = it * 256 + tid;                         // 0..2047
      int j = u >> 4, i8 = (u & 15) * 8;
      unsigned short v[8];
#pragma unroll
      for (int ii = 0; ii < 8; ii++) v[ii] = T[(i8 + ii) * 130 + j];
      *(u16x8_t*)&Wot[(size_t)(c0 + j) * 1024 + r0 + i8] = *(const u16x8_t*)v;
    }
  }
}

// ---------------- GEMM core (128x128 tile, BK=32, K=1024, B^T input) ----------------
// R11: byte-exact revert to the R5 structure — best measured (gemm_qkv 72us).
// Evidence closed this loop: explicit vmcnt pipeline (R6-8: 87us) and BK=64
// (R10: 87us, +35% HBM from L2 thrash) both regress vs the compiler-scheduled
// 2-barrier BK=32 loop. The only change vs R5 is MORE TLP via launch_bounds
// (3->4 blocks/CU) in the callers: LDS 24.5KB fits 6 blocks, VGPR 80 <= 128,
// so the extra resident block costs nothing and fills barrier-drain windows.

static __device__ __forceinline__ void gemm_core(const unsigned short* __restrict__ A,
    const unsigned short* __restrict__ Bt, unsigned short* As, unsigned short* Bs,
    int bm, int bn, f4_t acc[4][4])
{
  const int tid = threadIdx.x, w = tid >> 6, lane = tid & 63;
  const int quad = lane >> 4, col = lane & 15;
  const int wm = (w >> 1) * 64, wn = (w & 1) * 64;
  const int srow = lane >> 2;                         // 0..15
  const int goff = (((lane & 3) ^ ((srow >> 1) & 3)) * 8);
  const unsigned short* ga = A  + (size_t)(bm + 32 * w + srow) * D_ + goff;
  const unsigned short* gb = Bt + (size_t)(bn + 32 * w + srow) * D_ + goff;
  unsigned short* lAs0 = &As[(32 * w) * 32];
  unsigned short* lAs1 = &As[(32 * w + 16) * 32];
  unsigned short* lBs0 = &Bs[(32 * w) * 32];
  unsigned short* lBs1 = &Bs[(32 * w + 16) * 32];
  const int psw = (quad ^ ((col >> 1) & 3)) * 8;

  for (int k0 = 0; k0 < D_; k0 += 32) {
    __syncthreads();
    GLDS16(ga + k0,           lAs0);
    GLDS16(ga + 16 * D_ + k0, lAs1);
    GLDS16(gb + k0,           lBs0);
    GLDS16(gb + 16 * D_ + k0, lBs1);
    __syncthreads();
    bf8_t af[4], bfv[4];
#pragma unroll
    for (int mt = 0; mt < 4; mt++) af[mt]  = ldbf8(&As[(wm + 16 * mt + col) * 32 + psw]);
#pragma unroll
    for (int nt = 0; nt < 4; nt++) bfv[nt] = ldbf8(&Bs[(wn + 16 * nt + col) * 32 + psw]);
#pragma unroll
    for (int mt = 0; mt < 4; mt++)
#pragma unroll
      for (int nt = 0; nt < 4; nt++)
        acc[mt][nt] = MFMA16(af[mt], bfv[nt], acc[mt][nt]);
  }
}

// ---------------- stage 1: QKV projection (R5 structure, 4 blocks/CU) --------

__global__ __launch_bounds__(256, 4) void gemm_qkv(const unsigned short* __restrict__ A,
    const unsigned short* __restrict__ Bt,
    unsigned short* __restrict__ Qp, unsigned short* __restrict__ Kp,
    unsigned short* __restrict__ Vtp)
{
  __shared__ __align__(16) unsigned short As[128 * 32];
  __shared__ __align__(16) unsigned short Bs[128 * 32];
  __shared__ __align__(16) unsigned short Cs[32 * 136];   // 8.7 KB epilogue tile
  f4_t acc[4][4] = {};
  const int bm = blockIdx.y * 128, bn = blockIdx.x * 128;
  gemm_core(A, Bt, As, Bs, bm, bn, acc);

  const int tid = threadIdx.x, w = tid >> 6, lane = tid & 63;
  const int quad = lane >> 4, col = lane & 15;
  const int wn = (w & 1) * 64;
  const int qkv = bn >> 10;

  if (qkv == 2) {
    const int wm = (w >> 1) * 64;
#pragma unroll
    for (int nt = 0; nt < 4; nt++) {
      int n = bn + wn + 16 * nt + col;
      int r1 = n & 1023, h = r1 >> 6, dh = r1 & 63;
#pragma unroll
      for (int mt = 0; mt < 4; mt++) {
        int m0 = bm + wm + 16 * mt + quad * 4;
        int b = m0 >> 11, s0 = m0 & 2047;
        unsigned int lo = f2bf(acc[mt][nt][0]) | ((unsigned int)f2bf(acc[mt][nt][1]) << 16);
        unsigned int hi = f2bf(acc[mt][nt][2]) | ((unsigned int)f2bf(acc[mt][nt][3]) << 16);
        *(uint2*)&Vtp[((size_t)(b * H_ + h) * DH_ + dh) * S_ + s0] = make_uint2(lo, hi);
      }
    }
    return;
  }

  const float qs = (qkv == 0) ? QSCALE : 1.0f;
  unsigned short* dst = (qkv == 0) ? Qp : Kp;
  const int h0 = (bn & 1023) >> 6;                    // this strip covers heads h0, h0+1
#pragma unroll
  for (int p = 0; p < 4; p++) {
    __syncthreads();
    if ((w >> 1) == (p >> 1)) {                       // 2 waves store rows [32p,32p+32)
#pragma unroll
      for (int mi = 0; mi < 2; mi++) {
        int mt = 2 * (p & 1) + mi;
        int lr0 = mi * 16 + quad * 4;
#pragma unroll
        for (int nt = 0; nt < 4; nt++) {
          int n = wn + nt * 16 + col;
#pragma unroll
          for (int r = 0; r < 4; r++)
            Cs[(lr0 + r) * 136 + n] = f2bf(acc[mt][nt][r] * qs);
        }
      }
    }
    __syncthreads();
#pragma unroll
    for (int it = 0; it < 2; it++) {
      int u = it * 256 + tid;                         // 0..511
      int lr = u >> 4, kk8 = u & 15;
      u16x8_t v = *(const u16x8_t*)&Cs[lr * 136 + kk8 * 8];
      int g = bm + 32 * p + lr;
      int b = g >> 11, s = g & 2047;
      int h = h0 + (kk8 >> 3), dh0 = (kk8 & 7) * 8;
      *(u16x8_t*)&dst[((size_t)(b * H_ + h) * S_ + s) * DH_ + dh0] = v;
    }
  }
}

// ---------------- stage 2: flash attention, S^T formulation ----------------
// grid(bh, qt): all 16 q-tiles of a head share blockIdx.x%8 -> same XCD L2.
// KVBLK 64, Ks/Vs double-buffered; stage(next) before compute(cur); fenced
// s_barrier + counted vmcnt(4) + LGKM0 before trailing barrier (R8, passing).
// R5: P never touches LDS OR cross-lane ops (free A-row permutation on QK^T).

__global__ __launch_bounds__(256, 4) void flash_attn(const unsigned short* __restrict__ Qp,
    const unsigned short* __restrict__ Kp, const unsigned short* __restrict__ Vtp,
    unsigned short* __restrict__ Cc)
{
  __shared__ __align__(16) unsigned short Ks[2][64 * 64];   // 2 x 8 KB
  __shared__ __align__(16) unsigned short Vs[2][64 * 64];   // 2 x 8 KB
  const int tid = threadIdx.x, w = tid >> 6, lane = tid & 63;
  const int quad = lane >> 4, col = lane & 15;
  const int bh = blockIdx.x, qt = blockIdx.y;

  const unsigned short* Qg = Qp + ((size_t)bh * S_ + qt * 128 + w * 32) * DH_;
  bf8_t aq[2][2];
#pragma unroll
  for (int t = 0; t < 2; t++)
#pragma unroll
    for (int kc = 0; kc < 2; kc++)
      aq[t][kc] = ldbf8(Qg + (t * 16 + col) * DH_ + kc * 32 + quad * 8);

  const bf8_t vones = __builtin_bit_cast(bf8_t, (u16x8_t)((unsigned short)0x3F80));
  f4_t o[2][4] = {};
  f4_t lacc[2] = {};

  const unsigned short* Kg0 = Kp  + (size_t)bh * S_ * DH_;
  const unsigned short* Vg0 = Vtp + (size_t)bh * DH_ * S_;

  const int rl8 = lane >> 3;                          // 0..7
  const int g8  = lane & 7;
  const int ksw0 = (g8 ^ (rl8 & 3)) * 8;
  const int ksw1 = (g8 ^ ((rl8 & 3) | 4)) * 8;
  const int vsw  = (g8 ^ rl8) * 8;
  const unsigned short* KgW = Kg0 + (size_t)(16 * w + rl8) * DH_;
  const unsigned short* VgW = Vg0 + (size_t)(16 * w + rl8) * S_ + vsw;

  auto stage = [&](int t, int bsel) {
    const unsigned short* Kg = KgW + (size_t)t * 64 * DH_;
    const unsigned short* Vg = VgW + t * 64;
    unsigned short* KsB = &Ks[bsel][(16 * w) * 64];
    unsigned short* VsB = &Vs[bsel][(16 * w) * 64];
    GLDS16(Kg + ksw0,           KsB);
    GLDS16(Kg + 8 * DH_ + ksw1, KsB + 8 * 64);
    GLDS16(Vg,                  VsB);
    GLDS16(Vg + (size_t)8 * S_, VsB + 8 * 64);
  };

  auto compute_tile = [&](const unsigned short* KsC, const unsigned short* VsC) {
#pragma unroll
    for (int hh = 0; hh < 2; hh++) {
      f4_t sc[2][2] = {};
      __builtin_amdgcn_s_setprio(1);
#pragma unroll
      for (int ctl = 0; ctl < 2; ctl++) {
        int krow = hh * 32 + (col >> 2) * 8 + ctl * 4 + (col & 3);
        int fk = (col & 3) | (((col >> 2) & 1) << 2);
#pragma unroll
        for (int kc = 0; kc < 2; kc++) {
          bf8_t bk = ldbf8(&KsC[krow * 64 + (((kc * 4 + quad) ^ fk) * 8)]);
          sc[0][ctl] = MFMA16(bk, aq[0][kc], sc[0][ctl]);
          sc[1][ctl] = MFMA16(bk, aq[1][kc], sc[1][ctl]);
        }
      }
      __builtin_amdgcn_s_setprio(0);

      // exp2 -> cvt_pk: words land directly in PV A-fragment order.
      bf8_t ap[2];
#pragma unroll
      for (int t = 0; t < 2; t++) {
        u32x4_t t4;
        t4[0] = pkbf(__builtin_amdgcn_exp2f(sc[t][0][0]),
                     __builtin_amdgcn_exp2f(sc[t][0][1]));
        t4[1] = pkbf(__builtin_amdgcn_exp2f(sc[t][0][2]),
                     __builtin_amdgcn_exp2f(sc[t][0][3]));
        t4[2] = pkbf(__builtin_amdgcn_exp2f(sc[t][1][0]),
                     __builtin_amdgcn_exp2f(sc[t][1][1]));
        t4[3] = pkbf(__builtin_amdgcn_exp2f(sc[t][1][2]),
                     __builtin_amdgcn_exp2f(sc[t][1][3]));
        ap[t] = __builtin_bit_cast(bf8_t, t4);
      }

      {
        __builtin_amdgcn_s_setprio(1);
        lacc[0] = MFMA16(ap[0], vones, lacc[0]);
        lacc[1] = MFMA16(ap[1], vones, lacc[1]);
        int gk = hh * 4 + quad;
#pragma unroll
        for (int cv = 0; cv < 4; cv++) {
          int vr = cv * 16 + col;
          bf8_t bv = ldbf8(&VsC[vr * 64 + ((gk ^ (vr & 7)) * 8)]);
          o[0][cv] = MFMA16(ap[0], bv, o[0][cv]);
          o[1][cv] = MFMA16(ap[1], bv, o[1][cv]);
        }
        __builtin_amdgcn_s_setprio(0);
      }
    }
  };

  stage(0, 0);
#pragma unroll 2
  for (int kt = 0; kt < S_ / 64 - 1; kt++) {
    stage(kt + 1, (kt + 1) & 1);
    asm volatile("s_waitcnt vmcnt(4)" ::: "memory");
    SBAR();
    compute_tile(&Ks[kt & 1][0], &Vs[kt & 1][0]);
    LGKM0();                                          // ds_reads done before WAR window
    SBAR();
  }
  asm volatile("s_waitcnt vmcnt(0)" ::: "memory");
  SBAR();
  compute_tile(&Ks[1][0], &Vs[1][0]);

  const int b = bh >> 4, h = bh & 15;
#pragma unroll
  for (int t = 0; t < 2; t++) {
    float linv[4];
#pragma unroll
    for (int r = 0; r < 4; r++)
      linv[r] = 1.0f / lacc[t][r];
#pragma unroll
    for (int cv = 0; cv < 4; cv++)
#pragma unroll
      for (int r = 0; r < 4; r++) {
        float v = o[t][cv][r] * linv[r];
        int s = qt * 128 + w * 32 + t * 16 + quad * 4 + r;
        int dcol = h * 64 + cv * 16 + col;
        Cc[((size_t)b * S_ + s) * D_ + dcol] = f2bf(v);
      }
  }
}

// ---------------- stage 3: output projection (R5 structure, 4 blocks/CU) -----
// f32 epilogue via 32x128 LDS tile -> 16B/lane coalesced stores.

__global__ __launch_bounds__(256, 4) void gemm_out(const unsigned short* __restrict__ A,
    const unsigned short* __restrict__ Bt, float* __restrict__ Out)
{
  __shared__ __align__(16) unsigned short As[128 * 32];
  __shared__ __align__(16) unsigned short Bs[128 * 32];
  __shared__ __align__(16) float Cf[32 * 132];            // 16.9 KB epilogue tile
  f4_t acc[4][4] = {};
  const int bm = blockIdx.y * 128, bn = blockIdx.x * 128;
  gemm_core(A, Bt, As, Bs, bm, bn, acc);

  const int tid = threadIdx.x, w = tid >> 6, lane = tid & 63;
  const int quad = lane >> 4, col = lane & 15;
  const int wn = (w & 1) * 64;
#pragma unroll
  for (int p = 0; p < 4; p++) {
    __syncthreads();
    if ((w >> 1) == (p >> 1)) {
#pragma unroll
      for (int mi = 0; mi < 2; mi++) {
        int mt = 2 * (p & 1) + mi;
        int lr0 = mi * 16 + quad * 4;
#pragma unroll
        for (int nt = 0; nt < 4; nt++) {
          int n = wn + nt * 16 + col;
#pragma unroll
          for (int r = 0; r < 4; r++)
            Cf[(lr0 + r) * 132 + n] = acc[mt][nt][r];
        }
      }
    }
    __syncthreads();
#pragma unroll
    for (int it = 0; it < 4; it++) {
      int u = it * 256 + tid;                         // 0..1023
      int lr = u >> 5, kk4 = u & 31;
      f4_t v = *(const f4_t*)&Cf[lr * 132 + kk4 * 4];
      int g = bm + 32 * p + lr;
      *(f4_t*)&Out[(size_t)g * D_ + bn + kk4 * 4] = v;
    }
  }
}

// ---------------- launch ----------------

extern "C" void kernel_launch(void* const* d_in, const int* in_sizes, int n_in,
                              void* d_out, int out_size, void* d_ws, size_t ws_size,
                              hipStream_t stream) {
  const float* x  = (const float*)d_in[0];
  const float* Wq = (const float*)d_in[1];
  const float* Wk = (const float*)d_in[2];
  const float* Wv = (const float*)d_in[3];
  const float* Wo = (const float*)d_in[4];
  float* out = (float*)d_out;

  char* ws = (char*)d_ws;
  size_t off = 0;
  auto alloc = [&](size_t bytes) -> void* {
    void* p = ws + off;
    off += (bytes + 255) & ~(size_t)255;
    return p;
  };
  unsigned short* xb   = (unsigned short*)alloc((size_t)M_ * D_ * 2);       // 16 MB
  unsigned short* Wcat = (unsigned short*)alloc((size_t)3 * D_ * D_ * 2);   // 6 MB
  unsigned short* Wot  = (unsigned short*)alloc((size_t)D_ * D_ * 2);       // 2 MB
  unsigned short* Qb   = (unsigned short*)alloc((size_t)B_ * H_ * S_ * DH_ * 2); // 16 MB
  unsigned short* Kb   = (unsigned short*)alloc((size_t)B_ * H_ * S_ * DH_ * 2); // 16 MB
  unsigned short* Vtb  = (unsigned short*)alloc((size_t)B_ * H_ * S_ * DH_ * 2); // 16 MB
  unsigned short* Cc   = (unsigned short*)alloc((size_t)M_ * D_ * 2);       // 16 MB

  cvt_all<<<8640, 256, 0, stream>>>(x, Wq, Wk, Wv, Wo, xb, Wcat, Wot);
  gemm_qkv<<<dim3(3 * D_ / 128, M_ / 128), 256, 0, stream>>>(xb, Wcat, Qb, Kb, Vtb);
  flash_attn<<<dim3(B_ * H_, S_ / 128), 256, 0, stream>>>(Qb, Kb, Vtb, Cc);
  gemm_out<<<dim3(D_ / 128, M_ / 128), 256, 0, stream>>>(Cc, Wot, out);
}

// Round 12
// 255.240 us; speedup vs baseline: 1.0795x; 1.0795x over previous
//
#include <hip/hip_runtime.h>

// Problem constants
#define B_  4
#define S_  2048
#define D_  1024
#define H_  16
#define DH_ 64
#define M_  (B_*S_)   // 8192

typedef __bf16 bf8_t __attribute__((ext_vector_type(8)));
typedef float f4_t __attribute__((ext_vector_type(4)));
typedef unsigned short u16x8_t __attribute__((ext_vector_type(8)));
typedef unsigned int u32x4_t __attribute__((ext_vector_type(4)));

static __device__ __forceinline__ unsigned short f2bf(float f) {
  return __builtin_bit_cast(unsigned short, (__bf16)f);
}
static __device__ __forceinline__ bf8_t ldbf8(const unsigned short* p) {
  return __builtin_bit_cast(bf8_t, *(const u16x8_t*)p);
}
// pack two f32 -> (bf16(b)<<16)|bf16(a): single VOP3 cvt_pk (RNE)
static __device__ __forceinline__ unsigned int pkbf(float a, float b) {
  unsigned int r;
  asm("v_cvt_pk_bf16_f32 %0, %1, %2" : "=v"(r) : "v"(a), "v"(b));
  return r;
}
#define MFMA16(a,b,c) __builtin_amdgcn_mfma_f32_16x16x32_bf16((a),(b),(c),0,0,0)
#define GLDS16(gp, lp) __builtin_amdgcn_global_load_lds( \
    (const __attribute__((address_space(1))) void*)(gp), \
    (__attribute__((address_space(3))) void*)(lp), 16, 0, 0)
#define SBAR() asm volatile("s_barrier" ::: "memory")
#define LGKM0() asm volatile("s_waitcnt lgkmcnt(0)" ::: "memory")

// 0.125 (1/sqrt(dh)) * log2(e): folded into Q so softmax uses bare exp2.
#define QSCALE 0.18033688011112042f

// ---------------- fused convert kernel ----------------
// blocks [0,8192): x->bf16 (coalesced both sides)
// blocks [8192,8576): Wq/Wk/Wv -> Wcat^T via LDS tile (64dh x 128k per block)
// blocks [8576,8640): Wo -> Wot^T via LDS tile (128x128)

__global__ void cvt_all(const float* __restrict__ x,
                        const float* __restrict__ Wq, const float* __restrict__ Wk,
                        const float* __restrict__ Wv, const float* __restrict__ Wo,
                        unsigned short* __restrict__ xb, unsigned short* __restrict__ Wcat,
                        unsigned short* __restrict__ Wot) {
  __shared__ unsigned short T[128 * 130];             // 33.3 KB, used by transpose parts
  const int blk = blockIdx.x, tid = threadIdx.x;
  if (blk < 8192) {
    int i = blk * 256 + tid;                          // over M_*D_/4
    float4 v = ((const float4*)x)[i];
    unsigned int lo = f2bf(v.x) | ((unsigned int)f2bf(v.y) << 16);
    unsigned int hi = f2bf(v.z) | ((unsigned int)f2bf(v.w) << 16);
    ((uint2*)xb)[i] = make_uint2(lo, hi);
  } else if (blk < 8576) {
    // W (H,D,DH) slab: qkv/h from bid>>3, k-chunk 128 from bid&7.
    int bid = blk - 8192;
    int qh = bid >> 3, kc = bid & 7;
    int qkv = qh >> 4, h = qh & 15;
    const float* W = (qkv == 0) ? Wq : (qkv == 1 ? Wk : Wv);
    const float* src = W + (size_t)h * 65536 + (size_t)kc * 128 * 64;
    // load 128k x 64dh coalesced -> T[k][dh] (pad 66)
#pragma unroll
    for (int jj = 0; jj < 32; jj++) {
      int idx = jj * 256 + tid;                       // kl = idx>>6, dh = idx&63
      T[(idx >> 6) * 66 + (idx & 63)] = f2bf(src[idx]);
    }
    __syncthreads();
    // gather columns -> coalesced 16B writes: Wcat[n0+dh][kc*128 + k]
    int n0 = qkv * 1024 + h * 64;
#pragma unroll
    for (int it = 0; it < 4; it++) {
      int u = it * 256 + tid;                         // 0..1023
      int dh = u >> 4, k8 = (u & 15) * 8;
      unsigned short v[8];
#pragma unroll
      for (int ii = 0; ii < 8; ii++) v[ii] = T[(k8 + ii) * 66 + dh];
      *(u16x8_t*)&Wcat[(size_t)(n0 + dh) * 1024 + kc * 128 + k8] =
          *(const u16x8_t*)v;
    }
  } else {
    // Wo (D,D) row-major -> Wot[n][k]; 128x128 tile
    int bid = blk - 8576;
    int r0 = (bid >> 3) * 128, c0 = (bid & 7) * 128;  // r0: k-dim, c0: n-dim
#pragma unroll
    for (int jj = 0; jj < 64; jj++) {
      int idx = jj * 256 + tid;                       // i = idx>>7, j = idx&127
      int i = idx >> 7, j = idx & 127;
      T[i * 130 + j] = f2bf(Wo[(size_t)(r0 + i) * 1024 + c0 + j]);
    }
    __syncthreads();
#pragma unroll
    for (int it = 0; it < 8; it++) {
      int u = it * 256 + tid;                         // 0..2047
      int j = u >> 4, i8 = (u & 15) * 8;
      unsigned short v[8];
#pragma unroll
      for (int ii = 0; ii < 8; ii++) v[ii] = T[(i8 + ii) * 130 + j];
      *(u16x8_t*)&Wot[(size_t)(c0 + j) * 1024 + r0 + i8] = *(const u16x8_t*)v;
    }
  }
}

// ---------------- GEMM core (128x128 tile, BK=32, K=1024, B^T input) ----------------
// R12: the guide's T3 "minimum 2-phase" recipe built ONLY from __syncthreads
// (correct by construction — every prior deviation failed: R6-8 asm barriers
// raced; R10 BK=64 thrashed L2; R11 bound-4 squeezed VGPR). Double-buffered
// staging; per K-step: STAGE(next tile, other buffer) -> compute(cur) ->
// ONE __syncthreads (drains my ds_reads + the prefetch, barrier). Staging
// latency hides under compute; barriers per kernel halve (64 -> 33).
// SM layout (shorts): A0 @0, A1 @4096, B0 @8192, B1 @12288 (32 KB).
// Epilogue Cs/Cf kept SEPARATE (byte-identical R5 epilogues): qkv LDS 40.7 KB,
// out 48.9 KB -> 3 blocks/CU, same as R5.

static __device__ __forceinline__ void gemm_core(const unsigned short* __restrict__ A,
    const unsigned short* __restrict__ Bt, unsigned short* SM,
    int bm, int bn, f4_t acc[4][4])
{
  const int tid = threadIdx.x, w = tid >> 6, lane = tid & 63;
  const int quad = lane >> 4, col = lane & 15;
  const int wm = (w >> 1) * 64, wn = (w & 1) * 64;
  const int srow = lane >> 2;                         // 0..15
  const int goff = (((lane & 3) ^ ((srow >> 1) & 3)) * 8);
  const unsigned short* ga = A  + (size_t)(bm + 32 * w + srow) * D_ + goff;
  const unsigned short* gb = Bt + (size_t)(bn + 32 * w + srow) * D_ + goff;
  const int psw = (quad ^ ((col >> 1) & 3)) * 8;
  const int sA = (32 * w) * 32;                       // wave slab offset

  auto stage = [&](int k0, int bsel) {
    unsigned short* As = SM + bsel * 4096;
    unsigned short* Bs = SM + 8192 + bsel * 4096;
    GLDS16(ga + k0,           &As[sA]);
    GLDS16(ga + 16 * D_ + k0, &As[sA + 512]);
    GLDS16(gb + k0,           &Bs[sA]);
    GLDS16(gb + 16 * D_ + k0, &Bs[sA + 512]);
  };
  auto compute = [&](int bsel) {
    const unsigned short* As = SM + bsel * 4096;
    const unsigned short* Bs = SM + 8192 + bsel * 4096;
    bf8_t af[4], bfv[4];
#pragma unroll
    for (int mt = 0; mt < 4; mt++) af[mt]  = ldbf8(&As[(wm + 16 * mt + col) * 32 + psw]);
#pragma unroll
    for (int nt = 0; nt < 4; nt++) bfv[nt] = ldbf8(&Bs[(wn + 16 * nt + col) * 32 + psw]);
#pragma unroll
    for (int mt = 0; mt < 4; mt++)
#pragma unroll
      for (int nt = 0; nt < 4; nt++)
        acc[mt][nt] = MFMA16(af[mt], bfv[nt], acc[mt][nt]);
  };

  stage(0, 0);
  __syncthreads();                                    // prologue: tile 0 landed
  for (int kt = 0; kt < D_ / 32 - 1; kt++) {
    stage((kt + 1) * 32, (kt + 1) & 1);               // prefetch next (other buf)
    compute(kt & 1);                                  // overlap with prefetch
    __syncthreads();                                  // drain prefetch + my reads
  }
  compute(1);                                         // tile 31 in buffer 1
}

// ---------------- stage 1: QKV projection (R5 epilogue, 2-phase core) --------

__global__ __launch_bounds__(256, 3) void gemm_qkv(const unsigned short* __restrict__ A,
    const unsigned short* __restrict__ Bt,
    unsigned short* __restrict__ Qp, unsigned short* __restrict__ Kp,
    unsigned short* __restrict__ Vtp)
{
  __shared__ __align__(16) unsigned short SM[16384];      // 32 KB staging dbuf
  __shared__ __align__(16) unsigned short Cs[32 * 136];   // 8.7 KB epilogue tile
  f4_t acc[4][4] = {};
  const int bm = blockIdx.y * 128, bn = blockIdx.x * 128;
  gemm_core(A, Bt, SM, bm, bn, acc);

  const int tid = threadIdx.x, w = tid >> 6, lane = tid & 63;
  const int quad = lane >> 4, col = lane & 15;
  const int wn = (w & 1) * 64;
  const int qkv = bn >> 10;

  if (qkv == 2) {
    const int wm = (w >> 1) * 64;
#pragma unroll
    for (int nt = 0; nt < 4; nt++) {
      int n = bn + wn + 16 * nt + col;
      int r1 = n & 1023, h = r1 >> 6, dh = r1 & 63;
#pragma unroll
      for (int mt = 0; mt < 4; mt++) {
        int m0 = bm + wm + 16 * mt + quad * 4;
        int b = m0 >> 11, s0 = m0 & 2047;
        unsigned int lo = f2bf(acc[mt][nt][0]) | ((unsigned int)f2bf(acc[mt][nt][1]) << 16);
        unsigned int hi = f2bf(acc[mt][nt][2]) | ((unsigned int)f2bf(acc[mt][nt][3]) << 16);
        *(uint2*)&Vtp[((size_t)(b * H_ + h) * DH_ + dh) * S_ + s0] = make_uint2(lo, hi);
      }
    }
    return;
  }

  const float qs = (qkv == 0) ? QSCALE : 1.0f;
  unsigned short* dst = (qkv == 0) ? Qp : Kp;
  const int h0 = (bn & 1023) >> 6;                    // this strip covers heads h0, h0+1
#pragma unroll
  for (int p = 0; p < 4; p++) {
    __syncthreads();
    if ((w >> 1) == (p >> 1)) {                       // 2 waves store rows [32p,32p+32)
#pragma unroll
      for (int mi = 0; mi < 2; mi++) {
        int mt = 2 * (p & 1) + mi;
        int lr0 = mi * 16 + quad * 4;
#pragma unroll
        for (int nt = 0; nt < 4; nt++) {
          int n = wn + nt * 16 + col;
#pragma unroll
          for (int r = 0; r < 4; r++)
            Cs[(lr0 + r) * 136 + n] = f2bf(acc[mt][nt][r] * qs);
        }
      }
    }
    __syncthreads();
#pragma unroll
    for (int it = 0; it < 2; it++) {
      int u = it * 256 + tid;                         // 0..511
      int lr = u >> 4, kk8 = u & 15;
      u16x8_t v = *(const u16x8_t*)&Cs[lr * 136 + kk8 * 8];
      int g = bm + 32 * p + lr;
      int b = g >> 11, s = g & 2047;
      int h = h0 + (kk8 >> 3), dh0 = (kk8 & 7) * 8;
      *(u16x8_t*)&dst[((size_t)(b * H_ + h) * S_ + s) * DH_ + dh0] = v;
    }
  }
}

// ---------------- stage 2: flash attention, S^T formulation ----------------
// grid(bh, qt): all 16 q-tiles of a head share blockIdx.x%8 -> same XCD L2.
// KVBLK 64, Ks/Vs double-buffered; stage(next) before compute(cur); fenced
// s_barrier + counted vmcnt(4) + LGKM0 before trailing barrier (R8, passing
// three times). P never touches LDS or cross-lane ops (R5 free permutation).

__global__ __launch_bounds__(256, 4) void flash_attn(const unsigned short* __restrict__ Qp,
    const unsigned short* __restrict__ Kp, const unsigned short* __restrict__ Vtp,
    unsigned short* __restrict__ Cc)
{
  __shared__ __align__(16) unsigned short Ks[2][64 * 64];   // 2 x 8 KB
  __shared__ __align__(16) unsigned short Vs[2][64 * 64];   // 2 x 8 KB
  const int tid = threadIdx.x, w = tid >> 6, lane = tid & 63;
  const int quad = lane >> 4, col = lane & 15;
  const int bh = blockIdx.x, qt = blockIdx.y;

  const unsigned short* Qg = Qp + ((size_t)bh * S_ + qt * 128 + w * 32) * DH_;
  bf8_t aq[2][2];
#pragma unroll
  for (int t = 0; t < 2; t++)
#pragma unroll
    for (int kc = 0; kc < 2; kc++)
      aq[t][kc] = ldbf8(Qg + (t * 16 + col) * DH_ + kc * 32 + quad * 8);

  const bf8_t vones = __builtin_bit_cast(bf8_t, (u16x8_t)((unsigned short)0x3F80));
  f4_t o[2][4] = {};
  f4_t lacc[2] = {};

  const unsigned short* Kg0 = Kp  + (size_t)bh * S_ * DH_;
  const unsigned short* Vg0 = Vtp + (size_t)bh * DH_ * S_;

  const int rl8 = lane >> 3;                          // 0..7
  const int g8  = lane & 7;
  const int ksw0 = (g8 ^ (rl8 & 3)) * 8;
  const int ksw1 = (g8 ^ ((rl8 & 3) | 4)) * 8;
  const int vsw  = (g8 ^ rl8) * 8;
  const unsigned short* KgW = Kg0 + (size_t)(16 * w + rl8) * DH_;
  const unsigned short* VgW = Vg0 + (size_t)(16 * w + rl8) * S_ + vsw;

  auto stage = [&](int t, int bsel) {
    const unsigned short* Kg = KgW + (size_t)t * 64 * DH_;
    const unsigned short* Vg = VgW + t * 64;
    unsigned short* KsB = &Ks[bsel][(16 * w) * 64];
    unsigned short* VsB = &Vs[bsel][(16 * w) * 64];
    GLDS16(Kg + ksw0,           KsB);
    GLDS16(Kg + 8 * DH_ + ksw1, KsB + 8 * 64);
    GLDS16(Vg,                  VsB);
    GLDS16(Vg + (size_t)8 * S_, VsB + 8 * 64);
  };

  auto compute_tile = [&](const unsigned short* KsC, const unsigned short* VsC) {
#pragma unroll
    for (int hh = 0; hh < 2; hh++) {
      f4_t sc[2][2] = {};
      __builtin_amdgcn_s_setprio(1);
#pragma unroll
      for (int ctl = 0; ctl < 2; ctl++) {
        int krow = hh * 32 + (col >> 2) * 8 + ctl * 4 + (col & 3);
        int fk = (col & 3) | (((col >> 2) & 1) << 2);
#pragma unroll
        for (int kc = 0; kc < 2; kc++) {
          bf8_t bk = ldbf8(&KsC[krow * 64 + (((kc * 4 + quad) ^ fk) * 8)]);
          sc[0][ctl] = MFMA16(bk, aq[0][kc], sc[0][ctl]);
          sc[1][ctl] = MFMA16(bk, aq[1][kc], sc[1][ctl]);
        }
      }
      __builtin_amdgcn_s_setprio(0);

      // exp2 -> cvt_pk: words land directly in PV A-fragment order.
      bf8_t ap[2];
#pragma unroll
      for (int t = 0; t < 2; t++) {
        u32x4_t t4;
        t4[0] = pkbf(__builtin_amdgcn_exp2f(sc[t][0][0]),
                     __builtin_amdgcn_exp2f(sc[t][0][1]));
        t4[1] = pkbf(__builtin_amdgcn_exp2f(sc[t][0][2]),
                     __builtin_amdgcn_exp2f(sc[t][0][3]));
        t4[2] = pkbf(__builtin_amdgcn_exp2f(sc[t][1][0]),
                     __builtin_amdgcn_exp2f(sc[t][1][1]));
        t4[3] = pkbf(__builtin_amdgcn_exp2f(sc[t][1][2]),
                     __builtin_amdgcn_exp2f(sc[t][1][3]));
        ap[t] = __builtin_bit_cast(bf8_t, t4);
      }

      {
        __builtin_amdgcn_s_setprio(1);
        lacc[0] = MFMA16(ap[0], vones, lacc[0]);
        lacc[1] = MFMA16(ap[1], vones, lacc[1]);
        int gk = hh * 4 + quad;
#pragma unroll
        for (int cv = 0; cv < 4; cv++) {
          int vr = cv * 16 + col;
          bf8_t bv = ldbf8(&VsC[vr * 64 + ((gk ^ (vr & 7)) * 8)]);
          o[0][cv] = MFMA16(ap[0], bv, o[0][cv]);
          o[1][cv] = MFMA16(ap[1], bv, o[1][cv]);
        }
        __builtin_amdgcn_s_setprio(0);
      }
    }
  };

  stage(0, 0);
#pragma unroll 2
  for (int kt = 0; kt < S_ / 64 - 1; kt++) {
    stage(kt + 1, (kt + 1) & 1);
    asm volatile("s_waitcnt vmcnt(4)" ::: "memory");
    SBAR();
    compute_tile(&Ks[kt & 1][0], &Vs[kt & 1][0]);
    LGKM0();                                          // ds_reads done before WAR window
    SBAR();
  }
  asm volatile("s_waitcnt vmcnt(0)" ::: "memory");
  SBAR();
  compute_tile(&Ks[1][0], &Vs[1][0]);

  const int b = bh >> 4, h = bh & 15;
#pragma unroll
  for (int t = 0; t < 2; t++) {
    float linv[4];
#pragma unroll
    for (int r = 0; r < 4; r++)
      linv[r] = 1.0f / lacc[t][r];
#pragma unroll
    for (int cv = 0; cv < 4; cv++)
#pragma unroll
      for (int r = 0; r < 4; r++) {
        float v = o[t][cv][r] * linv[r];
        int s = qt * 128 + w * 32 + t * 16 + quad * 4 + r;
        int dcol = h * 64 + cv * 16 + col;
        Cc[((size_t)b * S_ + s) * D_ + dcol] = f2bf(v);
      }
  }
}

// ---------------- stage 3: output projection (R5 epilogue, 2-phase core) -----
// f32 epilogue via 32x128 LDS tile -> 16B/lane coalesced stores.

__global__ __launch_bounds__(256, 3) void gemm_out(const unsigned short* __restrict__ A,
    const unsigned short* __restrict__ Bt, float* __restrict__ Out)
{
  __shared__ __align__(16) unsigned short SM[16384];      // 32 KB staging dbuf
  __shared__ __align__(16) float Cf[32 * 132];            // 16.9 KB epilogue tile
  f4_t acc[4][4] = {};
  const int bm = blockIdx.y * 128, bn = blockIdx.x * 128;
  gemm_core(A, Bt, SM, bm, bn, acc);

  const int tid = threadIdx.x, w = tid >> 6, lane = tid & 63;
  const int quad = lane >> 4, col = lane & 15;
  const int wn = (w & 1) * 64;
#pragma unroll
  for (int p = 0; p < 4; p++) {
    __syncthreads();
    if ((w >> 1) == (p >> 1)) {
#pragma unroll
      for (int mi = 0; mi < 2; mi++) {
        int mt = 2 * (p & 1) + mi;
        int lr0 = mi * 16 + quad * 4;
#pragma unroll
        for (int nt = 0; nt < 4; nt++) {
          int n = wn + nt * 16 + col;
#pragma unroll
          for (int r = 0; r < 4; r++)
            Cf[(lr0 + r) * 132 + n] = acc[mt][nt][r];
        }
      }
    }
    __syncthreads();
#pragma unroll
    for (int it = 0; it < 4; it++) {
      int u = it * 256 + tid;                         // 0..1023
      int lr = u >> 5, kk4 = u & 31;
      f4_t v = *(const f4_t*)&Cf[lr * 132 + kk4 * 4];
      int g = bm + 32 * p + lr;
      *(f4_t*)&Out[(size_t)g * D_ + bn + kk4 * 4] = v;
    }
  }
}

// ---------------- launch ----------------

extern "C" void kernel_launch(void* const* d_in, const int* in_sizes, int n_in,
                              void* d_out, int out_size, void* d_ws, size_t ws_size,
                              hipStream_t stream) {
  const float* x  = (const float*)d_in[0];
  const float* Wq = (const float*)d_in[1];
  const float* Wk = (const float*)d_in[2];
  const float* Wv = (const float*)d_in[3];
  const float* Wo = (const float*)d_in[4];
  float* out = (float*)d_out;

  char* ws = (char*)d_ws;
  size_t off = 0;
  auto alloc = [&](size_t bytes) -> void* {
    void* p = ws + off;
    off += (bytes + 255) & ~(size_t)255;
    return p;
  };
  unsigned short* xb   = (unsigned short*)alloc((size_t)M_ * D_ * 2);       // 16 MB
  unsigned short* Wcat = (unsigned short*)alloc((size_t)3 * D_ * D_ * 2);   // 6 MB
  unsigned short* Wot  = (unsigned short*)alloc((size_t)D_ * D_ * 2);       // 2 MB
  unsigned short* Qb   = (unsigned short*)alloc((size_t)B_ * H_ * S_ * DH_ * 2); // 16 MB
  unsigned short* Kb   = (unsigned short*)alloc((size_t)B_ * H_ * S_ * DH_ * 2); // 16 MB
  unsigned short* Vtb  = (unsigned short*)alloc((size_t)B_ * H_ * S_ * DH_ * 2); // 16 MB
  unsigned short* Cc   = (unsigned short*)alloc((size_t)M_ * D_ * 2);       // 16 MB

  cvt_all<<<8640, 256, 0, stream>>>(x, Wq, Wk, Wv, Wo, xb, Wcat, Wot);
  gemm_qkv<<<dim3(3 * D_ / 128, M_ / 128), 256, 0, stream>>>(xb, Wcat, Qb, Kb, Vtb);
  flash_attn<<<dim3(B_ * H_, S_ / 128), 256, 0, stream>>>(Qb, Kb, Vtb, Cc);
  gemm_out<<<dim3(D_ / 128, M_ / 128), 256, 0, stream>>>(Cc, Wot, out);
}